// Round 4
// baseline (175.255 us; speedup 1.0000x reference)
//
#include <hip/hip_runtime.h>
#include <hip/hip_fp16.h>
#include <math.h>

#define DIM 128
#define NVOX (DIM*DIM*DIM)

// clang native vector types (HIP's float4/uint4 are classes — rejected by
// __builtin_nontemporal_load/store)
typedef float vfloat4 __attribute__((ext_vector_type(4)));
typedef float vfloat2 __attribute__((ext_vector_type(2)));
typedef unsigned int vuint4 __attribute__((ext_vector_type(4)));
typedef unsigned int vuint3 __attribute__((ext_vector_type(3)));  // sizeof==16
static_assert(sizeof(vuint3) == 16, "vuint3 must stride 16B over the AoS array");

// ---------------- Pass A: dti (6,NVOX) f32 SoA -> AoS fp16 16B/voxel ---------
// One warp corner = one global_load touching ONE cache line instead of
// 6 scalar loads into 6 separate 8MB planes (R4: L1-transaction-bound).
// 4 voxels/thread, nt loads (dti is dead after this pass; keep it out of
// L2/L3 so the aos array stays resident). Same XCD swizzle as pass B so each
// slab is written by the XCD that will gather from it.
__global__ __launch_bounds__(256) void pack_dti_kernel(
    const float* __restrict__ dti, vuint4* __restrict__ aos)
{
    const int bid = blockIdx.x;                    // 2048 blocks
    const int sb = ((bid & 7) << 8) | (bid >> 3);  // XCD i-slab swizzle
    const int id4 = (sb * 256 + (int)threadIdx.x) * 4;

    const vfloat4 v0 = __builtin_nontemporal_load(reinterpret_cast<const vfloat4*>(dti + 0 * NVOX + id4));
    const vfloat4 v1 = __builtin_nontemporal_load(reinterpret_cast<const vfloat4*>(dti + 1 * NVOX + id4));
    const vfloat4 v2 = __builtin_nontemporal_load(reinterpret_cast<const vfloat4*>(dti + 2 * NVOX + id4));
    const vfloat4 v3 = __builtin_nontemporal_load(reinterpret_cast<const vfloat4*>(dti + 3 * NVOX + id4));
    const vfloat4 v4 = __builtin_nontemporal_load(reinterpret_cast<const vfloat4*>(dti + 4 * NVOX + id4));
    const vfloat4 v5 = __builtin_nontemporal_load(reinterpret_cast<const vfloat4*>(dti + 5 * NVOX + id4));

    auto packone = [&](float a0, float a1, float a2, float a3, float a4,
                       float a5, int idx) {
        const __half2 h01 = __floats2half2_rn(a0, a1);
        const __half2 h23 = __floats2half2_rn(a2, a3);
        const __half2 h45 = __floats2half2_rn(a4, a5);
        vuint4 q;
        q.x = *reinterpret_cast<const unsigned int*>(&h01);
        q.y = *reinterpret_cast<const unsigned int*>(&h23);
        q.z = *reinterpret_cast<const unsigned int*>(&h45);
        q.w = 0u;
        aos[idx] = q;  // normal store: we WANT these lines in L2 for pass B
    };
    packone(v0.x, v1.x, v2.x, v3.x, v4.x, v5.x, id4 + 0);
    packone(v0.y, v1.y, v2.y, v3.y, v4.y, v5.y, id4 + 1);
    packone(v0.z, v1.z, v2.z, v3.z, v4.z, v5.z, id4 + 2);
    packone(v0.w, v1.w, v2.w, v3.w, v4.w, v5.w, id4 + 3);
}

// ---- fp32 polar factor: branch-free 3 scaled + 2 unscaled Newton ------------
// Fixed point: R = U @ Vh (SVD polar factor), sign(det) preserved.
// For cond<=2e3: scaled iters contract sigma-range 22 -> 2.5 -> 1.1, then
// unscaled e^2/2: 0.1 -> 5e-3 -> 1.3e-5 (orthogonality error; output
// perturbation ~1e-4 << fp16-pack absmax 0.0156).
// Returns bad=true for cond_F(J) > 2e3 (caller redoes in fp64).
__device__ __forceinline__ bool polar_f32(const float J[9], float X[9])
{
#pragma unroll
    for (int t = 0; t < 9; ++t) X[t] = J[t];
    bool bad = false;
#pragma unroll
    for (int it = 0; it < 5; ++it) {
        float C[9];
        C[0] = X[4] * X[8] - X[5] * X[7];
        C[1] = X[5] * X[6] - X[3] * X[8];
        C[2] = X[3] * X[7] - X[4] * X[6];
        C[3] = X[2] * X[7] - X[1] * X[8];
        C[4] = X[0] * X[8] - X[2] * X[6];
        C[5] = X[1] * X[6] - X[0] * X[7];
        C[6] = X[1] * X[5] - X[2] * X[4];
        C[7] = X[2] * X[3] - X[0] * X[5];
        C[8] = X[0] * X[4] - X[1] * X[3];
        const float det = X[0] * C[0] + X[1] * C[1] + X[2] * C[2];
        float a, b;
        if (it < 3) {
            float nX = 0.0f, nC = 0.0f;
#pragma unroll
            for (int t = 0; t < 9; ++t) { nX += X[t] * X[t]; nC += C[t] * C[t]; }
            if (it == 0)
                bad = !(nX * nC < 4.0e6f * det * det);  // condF > 2e3 (sqrt-free)
            // s = ||C||/||X||; r = 1/sqrt(s*|det|); a = 0.5*s*r = 0.5*g;
            // b = 0.5*r*sign(det)  (g = sqrt(s/|det|), b = 0.5/(g*det))
            const float s = __builtin_amdgcn_sqrtf(nC * __builtin_amdgcn_rcpf(nX));
            const float r = __builtin_amdgcn_rsqf(s * fabsf(det));
            a = 0.5f * s * r;
            b = copysignf(0.5f * r, det);
        } else {
            a = 0.5f;
            b = 0.5f * __builtin_amdgcn_rcpf(det);
        }
#pragma unroll
        for (int t = 0; t < 9; ++t) X[t] = a * X[t] + b * C[t];
    }
    return bad;
}

// ---- fp64 fallback (rare; inline & unrolled => register-resident; a
// noinline call made these arrays addressable -> ~220MB scratch spill in R2) --
__device__ __forceinline__ void polar_f64(const float J[9], float X[9])
{
    double Y[9];
#pragma unroll
    for (int t = 0; t < 9; ++t) Y[t] = (double)J[t];
    for (int it = 0; it < 20; ++it) {
        double C[9];
        C[0] = Y[4] * Y[8] - Y[5] * Y[7];
        C[1] = Y[5] * Y[6] - Y[3] * Y[8];
        C[2] = Y[3] * Y[7] - Y[4] * Y[6];
        C[3] = Y[2] * Y[7] - Y[1] * Y[8];
        C[4] = Y[0] * Y[8] - Y[2] * Y[6];
        C[5] = Y[1] * Y[6] - Y[0] * Y[7];
        C[6] = Y[1] * Y[5] - Y[2] * Y[4];
        C[7] = Y[2] * Y[3] - Y[0] * Y[5];
        C[8] = Y[0] * Y[4] - Y[1] * Y[3];
        const double det = Y[0] * C[0] + Y[1] * C[1] + Y[2] * C[2];
        if (!(fabs(det) > 1e-300)) break;
        double nX = 0.0, nC = 0.0;
#pragma unroll
        for (int t = 0; t < 9; ++t) { nX += Y[t] * Y[t]; nC += C[t] * C[t]; }
        const double g = sqrt(sqrt(nC) / (fabs(det) * sqrt(nX)));
        const double a = 0.5 * g;
        const double b = 0.5 / (g * det);
        double diff2 = 0.0, n2 = 0.0;
#pragma unroll
        for (int t = 0; t < 9; ++t) {
            const double y = a * Y[t] + b * C[t];
            const double d = y - Y[t];
            diff2 += d * d; n2 += y * y;
            Y[t] = y;
        }
        if (diff2 <= 1e-26 * n2) break;
    }
#pragma unroll
    for (int t = 0; t < 9; ++t) X[t] = (float)Y[t];
}

// ---------------- Pass B: warp + polar + congruence --------------------------
// R8: TWO k-adjacent voxels per thread. R6/R7 showed the scheduler re-sinks
// hoisted loads to their uses (sched_barrier can't pin loads it has no dep
// edge to), so single-chain latency stays exposed (VALUBusy ~62%, 36% stall).
// Dual independent chains make the ILP structural: when chain A waits on a
// load, chain B issues — no scheduling directive needed. k-pairing also
// vectorizes ddf loads (float2) and out stores (float2), halving those
// instruction counts, and the 16 gathers share ~half their cache lines.
__global__ __launch_bounds__(256) void warp_dti_kernel(
    const vuint3* __restrict__ aos,
    const float* __restrict__ ddf,
    float* __restrict__ out)
{
    const int bid = blockIdx.x;                     // 4096 blocks
    const int sb = ((bid & 7) << 9) | (bid >> 3);   // XCD i-slab swizzle
    const int p = sb * 256 + (int)threadIdx.x;      // voxel-pair index
    const int vid = p << 1;                          // even voxel id
    const int k0 = vid & (DIM - 1);                  // even; k1 = k0+1
    const int j = (vid >> 7) & (DIM - 1);
    const int i = vid >> 14;

    const float* __restrict__ p0_ = ddf;
    const float* __restrict__ p1_ = ddf + NVOX;
    const float* __restrict__ p2_ = ddf + 2 * NVOX;

    // ---- neighbor geometry (shared i/j between the pair) ----
    const int im = (i > 0) ? i - 1 : 0, ip = (i < DIM - 1) ? i + 1 : DIM - 1;
    const int jm = (j > 0) ? j - 1 : 0, jp = (j < DIM - 1) ? j + 1 : DIM - 1;
    const float si = (ip - im == 2) ? 0.5f : 1.0f;
    const float sj = (jp - jm == 2) ? 0.5f : 1.0f;
    // k-gradient: central values come from the u-pair itself; only the two
    // outer scalars are extra loads. k0 even => k1=k0+1 always valid.
    const int km0 = (k0 > 0) ? k0 - 1 : 0;             // clamp -> val(k0)
    const int kp1 = (k0 + 2 < DIM) ? k0 + 2 : DIM - 1; // clamp -> val(k1)
    const float sk0 = (k0 > 0) ? 0.5f : 1.0f;
    const float sk1 = (k0 + 2 < DIM) ? 0.5f : 1.0f;

    const int l_ip = (ip << 14) | (j << 7) | k0;
    const int l_im = (im << 14) | (j << 7) | k0;
    const int l_jp = (i << 14) | (jp << 7) | k0;
    const int l_jm = (i << 14) | (jm << 7) | k0;
    const int l_km = (i << 14) | (j << 7) | km0;
    const int l_kp = (i << 14) | (j << 7) | kp1;

    // ---- per-channel loads: 5 float2 + 2 scalars (x3 channels = 21 instr) --
    float2 uu[3], nI[3], nIm[3], nJ[3], nJm[3];
    float skm[3], skp[3];
#pragma unroll
    for (int c = 0; c < 3; ++c) {
        const float* __restrict__ pc = (c == 0) ? p0_ : (c == 1) ? p1_ : p2_;
        uu[c]  = *reinterpret_cast<const float2*>(pc + vid);
        nI[c]  = *reinterpret_cast<const float2*>(pc + l_ip);
        nIm[c] = *reinterpret_cast<const float2*>(pc + l_im);
        nJ[c]  = *reinterpret_cast<const float2*>(pc + l_jp);
        nJm[c] = *reinterpret_cast<const float2*>(pc + l_jm);
        skm[c] = pc[l_km];
        skp[c] = pc[l_kp];
    }

    // ---- Jacobians for both voxels ----
    float J0[9], J1[9];
#pragma unroll
    for (int c = 0; c < 3; ++c) {
        J0[c * 3 + 0] = (nI[c].x - nIm[c].x) * si;
        J0[c * 3 + 1] = (nJ[c].x - nJm[c].x) * sj;
        J0[c * 3 + 2] = (uu[c].y - skm[c]) * sk0;   // central: val(k1)-val(k0-1)
        J1[c * 3 + 0] = (nI[c].y - nIm[c].y) * si;
        J1[c * 3 + 1] = (nJ[c].y - nJm[c].y) * sj;
        J1[c * 3 + 2] = (skp[c] - uu[c].x) * sk1;   // central: val(k1+1)-val(k0)
    }
    J0[0] += 1.0f; J0[4] += 1.0f; J0[8] += 1.0f;
    J1[0] += 1.0f; J1[4] += 1.0f; J1[8] += 1.0f;

    // ---- trilinear gather setup for both voxels ----
    int base[2], ddx[2], ddy[2], ddz[2];
    float wfx[2], wfy[2], wfz[2];
#pragma unroll
    for (int v = 0; v < 2; ++v) {
        const float ux = (v == 0) ? uu[0].x : uu[0].y;
        const float uy = (v == 0) ? uu[1].x : uu[1].y;
        const float uz = (v == 0) ? uu[2].x : uu[2].y;
        const float cx = fminf(fmaxf((float)i + ux, 0.0f), (float)(DIM - 1));
        const float cy = fminf(fmaxf((float)j + uy, 0.0f), (float)(DIM - 1));
        const float cz = fminf(fmaxf((float)(k0 + v) + uz, 0.0f), (float)(DIM - 1));
        const float x0f = floorf(cx), y0f = floorf(cy), z0f = floorf(cz);
        wfx[v] = cx - x0f; wfy[v] = cy - y0f; wfz[v] = cz - z0f;
        const int x0 = (int)x0f, y0 = (int)y0f, z0 = (int)z0f;
        const int x1 = min(x0 + 1, DIM - 1);
        const int y1 = min(y0 + 1, DIM - 1);
        const int z1 = min(z0 + 1, DIM - 1);
        ddz[v] = z1 - z0;
        ddy[v] = (y1 - y0) << 7;
        ddx[v] = (x1 - x0) << 14;
        base[v] = (x0 << 14) | (y0 << 7) | z0;
    }

    // ---- issue all 16 gathers (two independent sets) ----
    vuint3 q[2][8];
#pragma unroll
    for (int v = 0; v < 2; ++v) {
        q[v][0] = aos[base[v]];
        q[v][1] = aos[base[v] + ddz[v]];
        q[v][2] = aos[base[v] + ddy[v]];
        q[v][3] = aos[base[v] + ddy[v] + ddz[v]];
        q[v][4] = aos[base[v] + ddx[v]];
        q[v][5] = aos[base[v] + ddx[v] + ddz[v]];
        q[v][6] = aos[base[v] + ddx[v] + ddy[v]];
        q[v][7] = aos[base[v] + ddx[v] + ddy[v] + ddz[v]];
    }

    // ---- two independent polar chains (compiler interleaves them) ----
    float X0[9], X1[9];
    const bool bad0 = polar_f32(J0, X0);
    const bool bad1 = polar_f32(J1, X1);

    // ---- interp accumulate for both voxels ----
    float acc[2][6];
#pragma unroll
    for (int v = 0; v < 2; ++v)
#pragma unroll
        for (int t = 0; t < 6; ++t) acc[v][t] = 0.0f;

    // fmaf((float)half, wt, acc) folds to v_fma_mix_f32 (f32 accumulate).
    auto gat = [&](const vuint3& qq, float wt, float* a) {
        const unsigned int qx = qq.x, qy = qq.y, qz = qq.z;
        const __half2 h01 = *reinterpret_cast<const __half2*>(&qx);
        const __half2 h23 = *reinterpret_cast<const __half2*>(&qy);
        const __half2 h45 = *reinterpret_cast<const __half2*>(&qz);
        a[0] = fmaf(__half2float(__low2half(h01)), wt, a[0]);
        a[1] = fmaf(__half2float(__high2half(h01)), wt, a[1]);
        a[2] = fmaf(__half2float(__low2half(h23)), wt, a[2]);
        a[3] = fmaf(__half2float(__high2half(h23)), wt, a[3]);
        a[4] = fmaf(__half2float(__low2half(h45)), wt, a[4]);
        a[5] = fmaf(__half2float(__high2half(h45)), wt, a[5]);
    };

#pragma unroll
    for (int v = 0; v < 2; ++v) {
        const float fx = wfx[v], fy = wfy[v], fz = wfz[v];
        const float gx0 = 1.0f - fx, gy0 = 1.0f - fy, gz0 = 1.0f - fz;
        gat(q[v][0], gx0 * gy0 * gz0, acc[v]);
        gat(q[v][1], gx0 * gy0 * fz,  acc[v]);
        gat(q[v][2], gx0 * fy * gz0,  acc[v]);
        gat(q[v][3], gx0 * fy * fz,   acc[v]);
        gat(q[v][4], fx * gy0 * gz0,  acc[v]);
        gat(q[v][5], fx * gy0 * fz,   acc[v]);
        gat(q[v][6], fx * fy * gz0,   acc[v]);
        gat(q[v][7], fx * fy * fz,    acc[v]);
    }

    // ---- rare ill-conditioned fallback ----
    if (__builtin_expect(bad0, 0)) polar_f64(J0, X0);
    if (__builtin_expect(bad1, 0)) polar_f64(J1, X1);

    // ---- Dp = R^T M R for both voxels; paired float2 nt stores ----
    float o[2][6];
#pragma unroll
    for (int v = 0; v < 2; ++v) {
        const float* X = (v == 0) ? X0 : X1;
        const float M00 = acc[v][0], M01 = acc[v][1], M11 = acc[v][2];
        const float M02 = acc[v][3], M12 = acc[v][4], M22 = acc[v][5];
        float P[9];  // P = M * R
        P[0] = M00 * X[0] + M01 * X[3] + M02 * X[6];
        P[1] = M00 * X[1] + M01 * X[4] + M02 * X[7];
        P[2] = M00 * X[2] + M01 * X[5] + M02 * X[8];
        P[3] = M01 * X[0] + M11 * X[3] + M12 * X[6];
        P[4] = M01 * X[1] + M11 * X[4] + M12 * X[7];
        P[5] = M01 * X[2] + M11 * X[5] + M12 * X[8];
        P[6] = M02 * X[0] + M12 * X[3] + M22 * X[6];
        P[7] = M02 * X[1] + M12 * X[4] + M22 * X[7];
        P[8] = M02 * X[2] + M12 * X[5] + M22 * X[8];
        o[v][0] = X[0] * P[0] + X[3] * P[3] + X[6] * P[6];
        o[v][1] = X[1] * P[0] + X[4] * P[3] + X[7] * P[6];
        o[v][2] = X[1] * P[1] + X[4] * P[4] + X[7] * P[7];
        o[v][3] = X[2] * P[0] + X[5] * P[3] + X[8] * P[6];
        o[v][4] = X[2] * P[1] + X[5] * P[4] + X[8] * P[7];
        o[v][5] = X[2] * P[2] + X[5] * P[5] + X[8] * P[8];
    }

    // Output: 48 MB, zero reuse -> non-temporal so it doesn't evict aos
    // from L2/L3 between gathers.
#pragma unroll
    for (int t = 0; t < 6; ++t) {
        vfloat2 w; w.x = o[0][t]; w.y = o[1][t];
        __builtin_nontemporal_store(w, reinterpret_cast<vfloat2*>(out + t * NVOX + vid));
    }
}

extern "C" void kernel_launch(void* const* d_in, const int* in_sizes, int n_in,
                              void* d_out, int out_size, void* d_ws, size_t ws_size,
                              hipStream_t stream) {
    const float* dti = (const float*)d_in[0];
    const float* ddf = (const float*)d_in[1];
    float* out = (float*)d_out;
    vuint4* aos = (vuint4*)d_ws;  // 2M voxels * 16 B = 32 MB scratch

    hipLaunchKernelGGL(pack_dti_kernel, dim3(NVOX / 1024), dim3(256), 0, stream,
                       dti, aos);
    hipLaunchKernelGGL(warp_dti_kernel, dim3(NVOX / 512), dim3(256), 0, stream,
                       (const vuint3*)aos, ddf, out);
}